// Round 1
// baseline (73.701 us; speedup 1.0000x reference)
//
#include <hip/hip_runtime.h>

#define NBINS 128
#define NFREQ 64
#define HDIM 128
#define NQ 16384
#define EPSF 1e-8f

// Pack {P_real, P_imag, -softplus(w_raw), mag_w} into f-major float4 array.
__global__ __launch_bounds__(256) void pack_kernel(
    const float* __restrict__ probes,
    const float* __restrict__ wraw,
    const float* __restrict__ mw,
    float4* __restrict__ packed) {
  int idx = blockIdx.x * 256 + threadIdx.x;
  if (idx >= NBINS * NFREQ) return;
  int b = idx >> 6;
  int f = idx & 63;
  float pr = probes[b * HDIM + f];
  float pi = probes[b * HDIM + NFREQ + f];
  float x  = wraw[b * NFREQ + f];
  // stable softplus: max(x,0) + log1p(exp(-|x|))
  float sp = fmaxf(x, 0.0f) + log1pf(expf(-fabsf(x)));
  float m  = mw[b * NFREQ + f];
  packed[f * NBINS + b] = make_float4(pr, pi, -sp, m);
}

__global__ __launch_bounds__(256) void scorer_kernel(
    const float* __restrict__ Q,
    const float4* __restrict__ packed,
    const float* __restrict__ bias,
    float* __restrict__ out) {
  __shared__ float4 qlds[32][64];  // {qr_n, qi_n, qmag, 0} per (query, freq)
  const int t = threadIdx.x;
  const int qbase = blockIdx.x * 32;

  // ---- Phase 1: normalize 32 queries into LDS ----
  {
    const int qi = t >> 3;          // 0..31 query within tile
    const int f0 = (t & 7) * 8;     // 8 freqs per thread
    const float* qp = Q + (size_t)(qbase + qi) * HDIM;
    float4 r0 = *reinterpret_cast<const float4*>(qp + f0);
    float4 r1 = *reinterpret_cast<const float4*>(qp + f0 + 4);
    float4 i0 = *reinterpret_cast<const float4*>(qp + NFREQ + f0);
    float4 i1 = *reinterpret_cast<const float4*>(qp + NFREQ + f0 + 4);
    float s = r0.x*r0.x + r0.y*r0.y + r0.z*r0.z + r0.w*r0.w
            + r1.x*r1.x + r1.y*r1.y + r1.z*r1.z + r1.w*r1.w
            + i0.x*i0.x + i0.y*i0.y + i0.z*i0.z + i0.w*i0.w
            + i1.x*i1.x + i1.y*i1.y + i1.z*i1.z + i1.w*i1.w;
    // reduce across the 8 threads sharing this query (groups never cross a wave)
    s += __shfl_xor(s, 1, 8);
    s += __shfl_xor(s, 2, 8);
    s += __shfl_xor(s, 4, 8);
    float inv = 1.0f / (__builtin_amdgcn_sqrtf(s) + EPSF);
    float re[8] = {r0.x, r0.y, r0.z, r0.w, r1.x, r1.y, r1.z, r1.w};
    float im[8] = {i0.x, i0.y, i0.z, i0.w, i1.x, i1.y, i1.z, i1.w};
    #pragma unroll
    for (int j = 0; j < 8; ++j) {
      float qr = re[j] * inv;
      float qim = im[j] * inv;
      float qm = __builtin_amdgcn_sqrtf(fmaf(qr, qr, fmaf(qim, qim, EPSF)));
      qlds[qi][f0 + j] = make_float4(qr, qim, qm, 0.0f);
    }
  }
  __syncthreads();

  // ---- Phase 2: lane = bin, wave = (bin-half, query-sixteenth) ----
  const int w = t >> 6;
  const int lane = t & 63;
  const int b = (w & 1) * 64 + lane;
  const int qoff = (w >> 1) * 16;
  const float bb = bias[b];

  float acc[16];
  #pragma unroll
  for (int q = 0; q < 16; ++q) acc[q] = 0.0f;

  #pragma unroll
  for (int fc = 0; fc < 4; ++fc) {
    // per-bin constants for this freq chunk, register-resident (64 VGPRs)
    float4 c[16];
    #pragma unroll
    for (int fi = 0; fi < 16; ++fi)
      c[fi] = packed[(fc * 16 + fi) * NBINS + b];  // coalesced, L2-resident
    #pragma unroll 4
    for (int fi = 0; fi < 16; ++fi) {
      #pragma unroll
      for (int q = 0; q < 16; ++q) {  // 16 independent acc chains for ILP
        float4 qv = qlds[qoff + q][fc * 16 + fi];  // wave-uniform broadcast
        float er = c[fi].x - qv.x;
        float ei = c[fi].y - qv.y;
        float d2 = fmaf(er, er, EPSF);
        d2 = fmaf(ei, ei, d2);
        float d = __builtin_amdgcn_sqrtf(d2);
        acc[q] = fmaf(d, c[fi].z, acc[q]);
        acc[q] = fmaf(qv.z, c[fi].w, acc[q]);
      }
    }
  }

  #pragma unroll
  for (int q = 0; q < 16; ++q) {
    out[(size_t)(qbase + qoff + q) * NBINS + b] = acc[q] + bb;
  }
}

extern "C" void kernel_launch(void* const* d_in, const int* in_sizes, int n_in,
                              void* d_out, int out_size, void* d_ws, size_t ws_size,
                              hipStream_t stream) {
  const float* Q      = (const float*)d_in[0];
  const float* probes = (const float*)d_in[1];
  const float* wraw   = (const float*)d_in[2];
  const float* mw     = (const float*)d_in[3];
  const float* bias   = (const float*)d_in[4];
  float* out = (float*)d_out;
  float4* packed = (float4*)d_ws;  // needs 128*64*16 = 128 KiB

  pack_kernel<<<(NBINS * NFREQ + 255) / 256, 256, 0, stream>>>(probes, wraw, mw, packed);
  scorer_kernel<<<NQ / 32, 256, 0, stream>>>(Q, packed, bias, out);
}

// Round 2
// 56.927 us; speedup vs baseline: 1.2946x; 1.2946x over previous
//
#include <hip/hip_runtime.h>

#define NBINS 128
#define NFREQ 64
#define HDIM 128
#define NQ 16384
#define EPSF 1e-8f

// d_ws layout:
//   [0, 128 KiB)              : packed probes float4 {pr, pi, -softplus(w), mw} at [f*NBINS + b]
//   [128 KiB, +12.58 MB)      : Qpk — per query, 8 chunks of 24 floats {qr[8], qi[8], qm[8]}
#define QPK_OFF_BYTES (128 * 1024)
#define QPK_STRIDE 192  // floats per query (8 chunks * 24)
#define WS_NEEDED ((size_t)QPK_OFF_BYTES + (size_t)NQ * QPK_STRIDE * 4)

// ---------- Prologue A: pack probes + weights (shared by both paths) ----------
__global__ __launch_bounds__(256) void pack_kernel(
    const float* __restrict__ probes,
    const float* __restrict__ wraw,
    const float* __restrict__ mw,
    float4* __restrict__ packed) {
  int idx = blockIdx.x * 256 + threadIdx.x;
  if (idx >= NBINS * NFREQ) return;
  int b = idx >> 6;
  int f = idx & 63;
  float pr = probes[b * HDIM + f];
  float pi = probes[b * HDIM + NFREQ + f];
  float x  = wraw[b * NFREQ + f];
  float sp = fmaxf(x, 0.0f) + log1pf(expf(-fabsf(x)));  // stable softplus
  float m  = mw[b * NFREQ + f];
  packed[f * NBINS + b] = make_float4(pr, pi, -sp, m);
}

// ---------- Prologue B: normalize Q, pack {qr,qi,qm} per 8-freq chunk ----------
__global__ __launch_bounds__(64) void qn_kernel(
    const float* __restrict__ Q, float* __restrict__ Qpk) {
  int q = blockIdx.x * 64 + threadIdx.x;
  if (q >= NQ) return;
  const float* qp = Q + (size_t)q * HDIM;
  float row[HDIM];
  #pragma unroll
  for (int k = 0; k < HDIM / 4; ++k)
    *reinterpret_cast<float4*>(&row[k * 4]) =
        *reinterpret_cast<const float4*>(qp + k * 4);
  float s = 0.0f;
  #pragma unroll
  for (int k = 0; k < HDIM; ++k) s = fmaf(row[k], row[k], s);
  float inv = 1.0f / (__builtin_amdgcn_sqrtf(s) + EPSF);
  float* op = Qpk + (size_t)q * QPK_STRIDE;
  #pragma unroll
  for (int fc = 0; fc < 8; ++fc) {
    float qr[8], qi[8], qm[8];
    #pragma unroll
    for (int j = 0; j < 8; ++j) {
      int f = fc * 8 + j;
      qr[j] = row[f] * inv;
      qi[j] = row[NFREQ + f] * inv;
      qm[j] = __builtin_amdgcn_sqrtf(fmaf(qr[j], qr[j], fmaf(qi[j], qi[j], EPSF)));
    }
    float* cp = op + fc * 24;
    *reinterpret_cast<float4*>(cp + 0)  = make_float4(qr[0], qr[1], qr[2], qr[3]);
    *reinterpret_cast<float4*>(cp + 4)  = make_float4(qr[4], qr[5], qr[6], qr[7]);
    *reinterpret_cast<float4*>(cp + 8)  = make_float4(qi[0], qi[1], qi[2], qi[3]);
    *reinterpret_cast<float4*>(cp + 12) = make_float4(qi[4], qi[5], qi[6], qi[7]);
    *reinterpret_cast<float4*>(cp + 16) = make_float4(qm[0], qm[1], qm[2], qm[3]);
    *reinterpret_cast<float4*>(cp + 20) = make_float4(qm[4], qm[5], qm[6], qm[7]);
  }
}

// ---------- Main: lane = bin, probes in VGPRs, queries via scalar loads ----------
__global__ __launch_bounds__(256) void scorer_fast(
    const float* __restrict__ Qpk,
    const float4* __restrict__ packed,
    const float* __restrict__ bias,
    float* __restrict__ out) {
  const int t = threadIdx.x;
  const int lane = t & 63;
  const int wv = __builtin_amdgcn_readfirstlane(t >> 6);  // force wave-uniform
  const int gw = blockIdx.x * 4 + wv;        // 4096 waves total
  const int qbase = (gw >> 1) * 8;           // 8 queries per wave
  const int b = (gw & 1) * 64 + lane;        // bin half per wave
  const float bb = bias[b];

  float acc[8];
  #pragma unroll
  for (int q = 0; q < 8; ++q) acc[q] = 0.0f;

  for (int fc = 0; fc < 8; ++fc) {           // 8-freq chunks, rolled
    float4 c[8];
    #pragma unroll
    for (int j = 0; j < 8; ++j)
      c[j] = packed[(fc * 8 + j) * NBINS + b];  // coalesced 1 KB, L2-hot
    #pragma unroll
    for (int q = 0; q < 8; ++q) {
      const float* qp = Qpk + (size_t)(qbase + q) * QPK_STRIDE + fc * 24;
      float4 r0 = *reinterpret_cast<const float4*>(qp + 0);   // uniform -> s_load
      float4 r1 = *reinterpret_cast<const float4*>(qp + 4);
      float4 i0 = *reinterpret_cast<const float4*>(qp + 8);
      float4 i1 = *reinterpret_cast<const float4*>(qp + 12);
      float4 m0 = *reinterpret_cast<const float4*>(qp + 16);
      float4 m1 = *reinterpret_cast<const float4*>(qp + 20);
      float qr[8] = {r0.x, r0.y, r0.z, r0.w, r1.x, r1.y, r1.z, r1.w};
      float qi[8] = {i0.x, i0.y, i0.z, i0.w, i1.x, i1.y, i1.z, i1.w};
      float qm[8] = {m0.x, m0.y, m0.z, m0.w, m1.x, m1.y, m1.z, m1.w};
      float a = acc[q];
      #pragma unroll
      for (int j = 0; j < 8; ++j) {
        float er = c[j].x - qr[j];
        float ei = c[j].y - qi[j];
        float d2 = fmaf(er, er, EPSF);
        d2 = fmaf(ei, ei, d2);
        float d = __builtin_amdgcn_sqrtf(d2);
        a = fmaf(d, c[j].z, a);
        a = fmaf(qm[j], c[j].w, a);
      }
      acc[q] = a;
    }
  }
  #pragma unroll
  for (int q = 0; q < 8; ++q)
    out[(size_t)(qbase + q) * NBINS + b] = acc[q] + bb;
}

// ---------- Fallback (round-0 kernel) if ws_size is too small ----------
__global__ __launch_bounds__(256) void scorer_fallback(
    const float* __restrict__ Q,
    const float4* __restrict__ packed,
    const float* __restrict__ bias,
    float* __restrict__ out) {
  __shared__ float4 qlds[32][64];
  const int t = threadIdx.x;
  const int qbase = blockIdx.x * 32;
  {
    const int qi = t >> 3;
    const int f0 = (t & 7) * 8;
    const float* qp = Q + (size_t)(qbase + qi) * HDIM;
    float4 r0 = *reinterpret_cast<const float4*>(qp + f0);
    float4 r1 = *reinterpret_cast<const float4*>(qp + f0 + 4);
    float4 i0 = *reinterpret_cast<const float4*>(qp + NFREQ + f0);
    float4 i1 = *reinterpret_cast<const float4*>(qp + NFREQ + f0 + 4);
    float s = r0.x*r0.x + r0.y*r0.y + r0.z*r0.z + r0.w*r0.w
            + r1.x*r1.x + r1.y*r1.y + r1.z*r1.z + r1.w*r1.w
            + i0.x*i0.x + i0.y*i0.y + i0.z*i0.z + i0.w*i0.w
            + i1.x*i1.x + i1.y*i1.y + i1.z*i1.z + i1.w*i1.w;
    s += __shfl_xor(s, 1, 8);
    s += __shfl_xor(s, 2, 8);
    s += __shfl_xor(s, 4, 8);
    float inv = 1.0f / (__builtin_amdgcn_sqrtf(s) + EPSF);
    float re[8] = {r0.x, r0.y, r0.z, r0.w, r1.x, r1.y, r1.z, r1.w};
    float im[8] = {i0.x, i0.y, i0.z, i0.w, i1.x, i1.y, i1.z, i1.w};
    #pragma unroll
    for (int j = 0; j < 8; ++j) {
      float qr = re[j] * inv;
      float qim = im[j] * inv;
      float qm = __builtin_amdgcn_sqrtf(fmaf(qr, qr, fmaf(qim, qim, EPSF)));
      qlds[qi][f0 + j] = make_float4(qr, qim, qm, 0.0f);
    }
  }
  __syncthreads();
  const int w = t >> 6;
  const int lane = t & 63;
  const int b = (w & 1) * 64 + lane;
  const int qoff = (w >> 1) * 16;
  const float bb = bias[b];
  float acc[16];
  #pragma unroll
  for (int q = 0; q < 16; ++q) acc[q] = 0.0f;
  #pragma unroll
  for (int fc = 0; fc < 4; ++fc) {
    float4 c[16];
    #pragma unroll
    for (int fi = 0; fi < 16; ++fi)
      c[fi] = packed[(fc * 16 + fi) * NBINS + b];
    #pragma unroll 4
    for (int fi = 0; fi < 16; ++fi) {
      #pragma unroll
      for (int q = 0; q < 16; ++q) {
        float4 qv = qlds[qoff + q][fc * 16 + fi];
        float er = c[fi].x - qv.x;
        float ei = c[fi].y - qv.y;
        float d2 = fmaf(er, er, EPSF);
        d2 = fmaf(ei, ei, d2);
        float d = __builtin_amdgcn_sqrtf(d2);
        acc[q] = fmaf(d, c[fi].z, acc[q]);
        acc[q] = fmaf(qv.z, c[fi].w, acc[q]);
      }
    }
  }
  #pragma unroll
  for (int q = 0; q < 16; ++q)
    out[(size_t)(qbase + qoff + q) * NBINS + b] = acc[q] + bb;
}

extern "C" void kernel_launch(void* const* d_in, const int* in_sizes, int n_in,
                              void* d_out, int out_size, void* d_ws, size_t ws_size,
                              hipStream_t stream) {
  const float* Q      = (const float*)d_in[0];
  const float* probes = (const float*)d_in[1];
  const float* wraw   = (const float*)d_in[2];
  const float* mw     = (const float*)d_in[3];
  const float* bias   = (const float*)d_in[4];
  float* out = (float*)d_out;
  float4* packed = (float4*)d_ws;
  float* Qpk = (float*)((char*)d_ws + QPK_OFF_BYTES);

  pack_kernel<<<(NBINS * NFREQ + 255) / 256, 256, 0, stream>>>(probes, wraw, mw, packed);
  if (ws_size >= WS_NEEDED) {
    qn_kernel<<<NQ / 64, 64, 0, stream>>>(Q, Qpk);
    scorer_fast<<<4096 / 4, 256, 0, stream>>>(Qpk, packed, bias, out);
  } else {
    scorer_fallback<<<NQ / 32, 256, 0, stream>>>(Q, packed, bias, out);
  }
}

// Round 3
// 51.107 us; speedup vs baseline: 1.4421x; 1.1139x over previous
//
#include <hip/hip_runtime.h>

#define NBINS 128
#define NFREQ 64
#define HDIM 128
#define NQ 16384
#define EPSF 1e-8f

// d_ws layout:
//   [0, 128 KiB)         : packed probes float4 {pr, pi, -softplus(w), mw} at [f*NBINS + b]
//   [128 KiB, +12.58 MB) : Qpk — per query, 8 chunks of 24 floats {qr[8], qi[8], qm[8]}
#define QPK_OFF_BYTES (128 * 1024)
#define QPK_STRIDE 192
#define WS_NEEDED ((size_t)QPK_OFF_BYTES + (size_t)NQ * QPK_STRIDE * 4)

#define QN_BLOCKS (NQ / 64)                       // 256 blocks, 64 queries each
#define PACK_BLOCKS ((NBINS * NFREQ + 255) / 256) // 32 blocks

// ---------- Fused prologue: Q-normalize (blocks 0..255) + probe pack (rest) ----------
__global__ __launch_bounds__(256) void prologue_kernel(
    const float* __restrict__ Q,
    const float* __restrict__ probes,
    const float* __restrict__ wraw,
    const float* __restrict__ mw,
    float4* __restrict__ packed,
    float* __restrict__ Qpk) {
  const int blk = blockIdx.x;
  const int t = threadIdx.x;
  if (blk < QN_BLOCKS) {
    // 4 lanes per query; lane l owns freqs [16l, 16l+16)
    const int l = t & 3;
    const int q = blk * 64 + (t >> 2);
    const float* qp = Q + (size_t)q * HDIM;
    float re[16], im[16];
    #pragma unroll
    for (int k = 0; k < 4; ++k) {
      *reinterpret_cast<float4*>(&re[k * 4]) =
          *reinterpret_cast<const float4*>(qp + 16 * l + k * 4);
      *reinterpret_cast<float4*>(&im[k * 4]) =
          *reinterpret_cast<const float4*>(qp + NFREQ + 16 * l + k * 4);
    }
    float s = 0.0f;
    #pragma unroll
    for (int k = 0; k < 16; ++k) {
      s = fmaf(re[k], re[k], s);
      s = fmaf(im[k], im[k], s);
    }
    s += __shfl_xor(s, 1, 4);
    s += __shfl_xor(s, 2, 4);
    const float inv = 1.0f / (__builtin_amdgcn_sqrtf(s) + EPSF);
    #pragma unroll
    for (int cc = 0; cc < 2; ++cc) {
      const int fc = 2 * l + cc;
      float qr[8], qi[8], qm[8];
      #pragma unroll
      for (int j = 0; j < 8; ++j) {
        const int k = cc * 8 + j;
        qr[j] = re[k] * inv;
        qi[j] = im[k] * inv;
        qm[j] = __builtin_amdgcn_sqrtf(fmaf(qr[j], qr[j], fmaf(qi[j], qi[j], EPSF)));
      }
      float* cp = Qpk + (size_t)q * QPK_STRIDE + fc * 24;
      *reinterpret_cast<float4*>(cp + 0)  = make_float4(qr[0], qr[1], qr[2], qr[3]);
      *reinterpret_cast<float4*>(cp + 4)  = make_float4(qr[4], qr[5], qr[6], qr[7]);
      *reinterpret_cast<float4*>(cp + 8)  = make_float4(qi[0], qi[1], qi[2], qi[3]);
      *reinterpret_cast<float4*>(cp + 12) = make_float4(qi[4], qi[5], qi[6], qi[7]);
      *reinterpret_cast<float4*>(cp + 16) = make_float4(qm[0], qm[1], qm[2], qm[3]);
      *reinterpret_cast<float4*>(cp + 20) = make_float4(qm[4], qm[5], qm[6], qm[7]);
    }
  } else {
    const int idx = (blk - QN_BLOCKS) * 256 + t;
    if (idx >= NBINS * NFREQ) return;
    const int b = idx >> 6;
    const int f = idx & 63;
    const float pr = probes[b * HDIM + f];
    const float pi = probes[b * HDIM + NFREQ + f];
    const float x = wraw[b * NFREQ + f];
    const float sp = fmaxf(x, 0.0f) + log1pf(expf(-fabsf(x)));  // stable softplus
    const float m = mw[b * NFREQ + f];
    packed[f * NBINS + b] = make_float4(pr, pi, -sp, m);
  }
}

// ---------- Main: wave = 8 queries x 64 bins x 32 freqs (f-split across wave pairs) ----------
__global__ __launch_bounds__(256, 7) void scorer3(
    const float* __restrict__ Qpk,
    const float4* __restrict__ packed,
    const float* __restrict__ bias,
    float* __restrict__ out) {
  __shared__ float part[2][8][64];  // [bin-half][q][lane] — lane-consecutive, conflict-free
  const int t = threadIdx.x;
  const int lane = t & 63;
  const int wv = __builtin_amdgcn_readfirstlane(t >> 6);
  const int h = wv & 1;        // bin half
  const int fh = wv >> 1;      // freq half
  const int qbase = blockIdx.x * 8;
  const int b = h * 64 + lane;

  float acc[8];
  #pragma unroll
  for (int q = 0; q < 8; ++q) acc[q] = 0.0f;

  for (int fci = 0; fci < 4; ++fci) {   // rolled: 4 chunks of 8 freqs in this half
    const int fc = fh * 4 + fci;
    float4 c[8];
    #pragma unroll
    for (int j = 0; j < 8; ++j)
      c[j] = packed[(fc * 8 + j) * NBINS + b];  // 1 KB coalesced, L1/L2-hot
    #pragma unroll
    for (int q = 0; q < 8; ++q) {
      const float* qp = Qpk + (size_t)(qbase + q) * QPK_STRIDE + fc * 24;
      float4 r0 = *reinterpret_cast<const float4*>(qp + 0);   // wave-uniform -> s_load
      float4 r1 = *reinterpret_cast<const float4*>(qp + 4);
      float4 i0 = *reinterpret_cast<const float4*>(qp + 8);
      float4 i1 = *reinterpret_cast<const float4*>(qp + 12);
      float4 m0 = *reinterpret_cast<const float4*>(qp + 16);
      float4 m1 = *reinterpret_cast<const float4*>(qp + 20);
      float qr[8] = {r0.x, r0.y, r0.z, r0.w, r1.x, r1.y, r1.z, r1.w};
      float qi[8] = {i0.x, i0.y, i0.z, i0.w, i1.x, i1.y, i1.z, i1.w};
      float qm[8] = {m0.x, m0.y, m0.z, m0.w, m1.x, m1.y, m1.z, m1.w};
      float a = acc[q];
      #pragma unroll
      for (int j = 0; j < 8; ++j) {
        float er = c[j].x - qr[j];
        float ei = c[j].y - qi[j];
        float d2 = fmaf(er, er, EPSF);
        d2 = fmaf(ei, ei, d2);
        float d = __builtin_amdgcn_sqrtf(d2);
        a = fmaf(d, c[j].z, a);
        a = fmaf(qm[j], c[j].w, a);
      }
      acc[q] = a;
    }
  }

  if (fh == 1) {
    #pragma unroll
    for (int q = 0; q < 8; ++q) part[h][q][lane] = acc[q];
  }
  __syncthreads();
  if (fh == 0) {
    const float bb = bias[b];
    #pragma unroll
    for (int q = 0; q < 8; ++q)
      out[(size_t)(qbase + q) * NBINS + b] = acc[q] + part[h][q][lane] + bb;
  }
}

// ---------- Fallback if ws too small (not expected) ----------
__global__ __launch_bounds__(256) void scorer_fallback(
    const float* __restrict__ Q,
    const float4* __restrict__ packed,
    const float* __restrict__ bias,
    float* __restrict__ out) {
  __shared__ float4 qlds[32][64];
  const int t = threadIdx.x;
  const int qbase = blockIdx.x * 32;
  {
    const int qi = t >> 3;
    const int f0 = (t & 7) * 8;
    const float* qp = Q + (size_t)(qbase + qi) * HDIM;
    float4 r0 = *reinterpret_cast<const float4*>(qp + f0);
    float4 r1 = *reinterpret_cast<const float4*>(qp + f0 + 4);
    float4 i0 = *reinterpret_cast<const float4*>(qp + NFREQ + f0);
    float4 i1 = *reinterpret_cast<const float4*>(qp + NFREQ + f0 + 4);
    float s = r0.x*r0.x + r0.y*r0.y + r0.z*r0.z + r0.w*r0.w
            + r1.x*r1.x + r1.y*r1.y + r1.z*r1.z + r1.w*r1.w
            + i0.x*i0.x + i0.y*i0.y + i0.z*i0.z + i0.w*i0.w
            + i1.x*i1.x + i1.y*i1.y + i1.z*i1.z + i1.w*i1.w;
    s += __shfl_xor(s, 1, 8);
    s += __shfl_xor(s, 2, 8);
    s += __shfl_xor(s, 4, 8);
    float inv = 1.0f / (__builtin_amdgcn_sqrtf(s) + EPSF);
    float re[8] = {r0.x, r0.y, r0.z, r0.w, r1.x, r1.y, r1.z, r1.w};
    float im[8] = {i0.x, i0.y, i0.z, i0.w, i1.x, i1.y, i1.z, i1.w};
    #pragma unroll
    for (int j = 0; j < 8; ++j) {
      float qr = re[j] * inv;
      float qim = im[j] * inv;
      float qm = __builtin_amdgcn_sqrtf(fmaf(qr, qr, fmaf(qim, qim, EPSF)));
      qlds[qi][f0 + j] = make_float4(qr, qim, qm, 0.0f);
    }
  }
  __syncthreads();
  const int w = t >> 6;
  const int lane = t & 63;
  const int b = (w & 1) * 64 + lane;
  const int qoff = (w >> 1) * 16;
  const float bb = bias[b];
  float acc[16];
  #pragma unroll
  for (int q = 0; q < 16; ++q) acc[q] = 0.0f;
  #pragma unroll
  for (int fc = 0; fc < 4; ++fc) {
    float4 c[16];
    #pragma unroll
    for (int fi = 0; fi < 16; ++fi)
      c[fi] = packed[(fc * 16 + fi) * NBINS + b];
    #pragma unroll 4
    for (int fi = 0; fi < 16; ++fi) {
      #pragma unroll
      for (int q = 0; q < 16; ++q) {
        float4 qv = qlds[qoff + q][fc * 16 + fi];
        float er = c[fi].x - qv.x;
        float ei = c[fi].y - qv.y;
        float d2 = fmaf(er, er, EPSF);
        d2 = fmaf(ei, ei, d2);
        float d = __builtin_amdgcn_sqrtf(d2);
        acc[q] = fmaf(d, c[fi].z, acc[q]);
        acc[q] = fmaf(qv.z, c[fi].w, acc[q]);
      }
    }
  }
  #pragma unroll
  for (int q = 0; q < 16; ++q)
    out[(size_t)(qbase + qoff + q) * NBINS + b] = acc[q] + bb;
}

extern "C" void kernel_launch(void* const* d_in, const int* in_sizes, int n_in,
                              void* d_out, int out_size, void* d_ws, size_t ws_size,
                              hipStream_t stream) {
  const float* Q      = (const float*)d_in[0];
  const float* probes = (const float*)d_in[1];
  const float* wraw   = (const float*)d_in[2];
  const float* mw     = (const float*)d_in[3];
  const float* bias   = (const float*)d_in[4];
  float* out = (float*)d_out;
  float4* packed = (float4*)d_ws;
  float* Qpk = (float*)((char*)d_ws + QPK_OFF_BYTES);

  if (ws_size >= WS_NEEDED) {
    prologue_kernel<<<QN_BLOCKS + PACK_BLOCKS, 256, 0, stream>>>(
        Q, probes, wraw, mw, packed, Qpk);
    scorer3<<<NQ / 8, 256, 0, stream>>>(Qpk, packed, bias, out);
  } else {
    prologue_kernel<<<QN_BLOCKS + PACK_BLOCKS, 256, 0, stream>>>(
        Q, probes, wraw, mw, packed, Qpk);  // qn output unused in fallback
    scorer_fallback<<<NQ / 32, 256, 0, stream>>>(Q, packed, bias, out);
  }
}